// Round 3
// baseline (2349.278 us; speedup 1.0000x reference)
//
#include <hip/hip_runtime.h>

#define F1 62400
#define O1 800
#define O2N 100
#define TT 300
#define BB 2
#define NW5 5           /* 5 x 64-bit t-words cover 300 steps */
#define NF 32           /* f-chunks */
#define FPC (F1/NF)     /* 1950 f per chunk */
#define NOC 13          /* ceil(800/64) o-chunks */
#define KSRM 77
#define KREF 11

typedef unsigned long long u64;

/* ---- ws layout (bytes) ---- */
#define OFF_CONST 0ull
#define OFF_Z1   1024ull
#define OFF_U1   (OFF_Z1 + 3840000ull)
#define OFF_Z2   (OFF_U1 + 3840000ull)
#define OFF_U2   (OFF_Z2 + 480000ull)
#define OFF_S1   (OFF_U2 + 480000ull)
#define OFF_FBM  (OFF_S1 + 1920000ull)
#define OFF_PART (OFF_FBM + 4992000ull)                 /* fbm: 2*62400*5*8 */
#define NEED_SPARSE (OFF_PART + 68157440ull)            /* part: 32*2*13*320*64*4 ~ 83.8 MB */

/* K0: SRM/REF kernels on device, fp64 rounded through fp32 (matches np.float32). */
__global__ void k0_init(double* c) {
    int k = threadIdx.x;
    if (k < KSRM) {
        double v = ((double)k / 10.0) * exp(1.0 - (double)k / 10.0);
        c[k] = (double)(float)v;
    }
    if (k < KREF) {
        double v = -20.0 * (double)k * exp(1.0 - (double)k);
        c[80 + k] = (double)(float)v;
    }
}

/* K1: transposed bitmask fbm[b][f][w]: bit j of word w = (x[b][f][w*64+j] > 0.5).
   One wave per (b,f): 5 coalesced 256B loads + ballots. */
__global__ __launch_bounds__(256) void k1_fbm(const float* __restrict__ x,
                                              u64* __restrict__ fbm) {
    int gw = (blockIdx.x * 256 + threadIdx.x) >> 6;
    int lane = threadIdx.x & 63;
    if (gw >= BB * F1) return;
    int b = gw / F1, f = gw % F1;
    const float* xrow = x + ((size_t)b * F1 + f) * TT;
    u64* mrow = fbm + ((size_t)b * F1 + f) * NW5;
    #pragma unroll
    for (int w = 0; w < NW5; ++w) {
        int t = w * 64 + lane;
        bool on = false;
        if (t < TT) on = xrow[t] > 0.5f;
        u64 m = __ballot(on);
        if (lane == 0) mrow[w] = m;
    }
}

/* K3o: outer-product accumulation. Block = (fc, oc, b), 5 waves; wave w owns
   t-word w. LDS acc[wave][64 t][64 o] fp32 (80 KB -> 2 blocks/CU). Mask word
   is wave-uniform -> divergence-free ctz walk; w1 read directly (lane-gather
   with 16x line reuse along f). No barriers (waves fully independent). */
__global__ __launch_bounds__(320) void k3o(const float* __restrict__ w1,
                                           const u64* __restrict__ fbm,
                                           float* __restrict__ part) {
    __shared__ float acc[NW5][64][64];
    int fc = blockIdx.x, oc = blockIdx.y, b = blockIdx.z;
    int wave = __builtin_amdgcn_readfirstlane(threadIdx.x >> 6);
    int lane = threadIdx.x & 63;
    int o = oc * 64 + lane;
    bool ovalid = (o < O1);
    int oc_ = ovalid ? o : (O1 - 1);

    float* a = &acc[wave][0][0];
    for (int i = lane; i < 64 * 64; i += 64) a[i] = 0.0f;

    const u64* mrow = fbm + ((size_t)b * F1 + fc * FPC) * NW5 + wave;
    const float* wbase = w1 + (size_t)oc_ * F1 + fc * FPC;

    #pragma unroll 2
    for (int r = 0; r < FPC; ++r) {
        u64 m = mrow[(size_t)r * NW5];
        float v = wbase[r];
        if (m) {
            do {
                int j = __builtin_ctzll(m);
                m &= m - 1;
                a[j * 64 + lane] += v;
            } while (m);
        }
    }

    if (ovalid) {
        size_t base = ((((size_t)fc * BB + b) * NOC + oc) * 320 + wave * 64) * 64 + lane;
        for (int j = 0; j < 64; ++j)
            part[base + (size_t)j * 64] = a[j * 64 + lane];
    }
}

/* K4: fp64 sum over 32 f-chunk partials -> z1[(b*800+o)][t] */
__global__ __launch_bounds__(256) void k4_sum(const float* __restrict__ part,
                                              double* __restrict__ z1) {
    int t = blockIdx.x, b = blockIdx.y;
    const size_t fcs = (size_t)BB * NOC * 320 * 64;
    for (int o = threadIdx.x; o < O1; o += 256) {
        int oc = o >> 6, ol = o & 63;
        size_t base = (((size_t)b * NOC + oc) * 320 + t) * 64 + ol;
        double s = 0.0;
        #pragma unroll 4
        for (int fc = 0; fc < NF; ++fc) s += (double)part[(size_t)fc * fcs + base];
        z1[((size_t)(b * O1 + o)) * TT + t] = s;
    }
}

/* dense fallback GEMM1 (used only if ws too small) */
__global__ __launch_bounds__(256) void k_dense_gemm1(const float* __restrict__ x,
                                                     const float* __restrict__ w1,
                                                     double* __restrict__ z1) {
    int lin = blockIdx.x;
    int ot = lin % 25; int tt = (lin / 25) % 5; int b = lin / 125;
    int t0 = tt * 64, o0 = ot * 32;
    __shared__ float xs[64][64];
    __shared__ float wsh[32][64];
    int ti = threadIdx.x & 63, og = threadIdx.x >> 6;
    double dacc[8] = {0, 0, 0, 0, 0, 0, 0, 0};
    for (int fc = 0; fc < F1; fc += 64) {
        __syncthreads();
        for (int e = threadIdx.x; e < 64 * 64; e += 256) {
            int r = e >> 6, c = e & 63;
            int t = t0 + c;
            xs[r][c] = (t < TT) ? x[((size_t)b * F1 + fc + r) * TT + t] : 0.0f;
        }
        for (int e = threadIdx.x; e < 32 * 64; e += 256) {
            int r = e >> 6, c = e & 63;
            wsh[r][c] = w1[(size_t)(o0 + r) * F1 + fc + c];
        }
        __syncthreads();
        float facc[8] = {0, 0, 0, 0, 0, 0, 0, 0};
        for (int ff = 0; ff < 64; ++ff) {
            float xv = xs[ff][ti];
            #pragma unroll
            for (int oo = 0; oo < 8; ++oo) facc[oo] += wsh[og * 8 + oo][ff] * xv;
        }
        #pragma unroll
        for (int oo = 0; oo < 8; ++oo) dacc[oo] += (double)facc[oo];
    }
    int t = t0 + ti;
    if (t < TT) {
        #pragma unroll
        for (int oo = 0; oo < 8; ++oo) {
            int o = o0 + og * 8 + oo;
            z1[((size_t)(b * O1 + o)) * TT + t] = dacc[oo];
        }
    }
}

/* K5: causal SRM-alpha conv (psp), fp64. grid = rows, threads = t */
__global__ __launch_bounds__(320) void k5_psp(const double* __restrict__ z,
                                              double* __restrict__ u,
                                              const double* __restrict__ cst) {
    int row = blockIdx.x;
    int t = threadIdx.x; if (t >= TT) return;
    const double* zr = z + (size_t)row * TT;
    int kmax = t < (KSRM - 1) ? t : (KSRM - 1);
    double acc = 0.0;
    for (int k = 0; k <= kmax; ++k) acc += cst[k] * zr[t - k];
    u[(size_t)row * TT + t] = acc;
}

/* K6: spike scan layer 1 -> s1 in (b,t,f) layout (f32, binary) */
__global__ __launch_bounds__(64) void k6_spike1(const double* __restrict__ u,
                                                float* __restrict__ s_out,
                                                const double* __restrict__ cst) {
    int row = blockIdx.x * 64 + threadIdx.x;
    if (row >= BB * O1) return;
    int b = row / O1, o = row % O1;
    double rk[KREF];
    #pragma unroll
    for (int d = 0; d < KREF; ++d) rk[d] = cst[80 + d];
    const double* ur = u + (size_t)row * TT;
    unsigned hist = 0;
    for (int t = 0; t < TT; ++t) {
        double ueff = ur[t];
        #pragma unroll
        for (int d = 1; d < KREF; ++d)
            if (hist & (1u << (d - 1))) ueff += rk[d];
        int sp = (ueff >= 10.0) ? 1 : 0;
        s_out[((size_t)(b * TT + t)) * O1 + o] = (float)sp;
        hist = (hist << 1) | (unsigned)sp;
    }
}

/* K7: GEMM2, fp64 acc. block = (b*100+o2); threads = t */
__global__ __launch_bounds__(320) void k7_gemm2(const float* __restrict__ s1,
                                                const float* __restrict__ w2,
                                                double* __restrict__ z2) {
    int bo = blockIdx.x;
    int t = threadIdx.x; if (t >= TT) return;
    int b = bo / O2N, o2 = bo % O2N;
    const float* srow = s1 + ((size_t)(b * TT + t)) * O1;
    const float* wrow = w2 + (size_t)o2 * O1;
    double acc = 0.0;
    for (int f = 0; f < O1; ++f) acc += (double)(wrow[f] * srow[f]);
    z2[(size_t)bo * TT + t] = acc;
}

/* K9: spike scan layer 2 -> output (b,o2,t) fp32 */
__global__ __launch_bounds__(64) void k9_spike2(const double* __restrict__ u,
                                                float* __restrict__ out,
                                                const double* __restrict__ cst) {
    int row = blockIdx.x * 64 + threadIdx.x;
    if (row >= BB * O2N) return;
    double rk[KREF];
    #pragma unroll
    for (int d = 0; d < KREF; ++d) rk[d] = cst[80 + d];
    const double* ur = u + (size_t)row * TT;
    unsigned hist = 0;
    for (int t = 0; t < TT; ++t) {
        double ueff = ur[t];
        #pragma unroll
        for (int d = 1; d < KREF; ++d)
            if (hist & (1u << (d - 1))) ueff += rk[d];
        int sp = (ueff >= 10.0) ? 1 : 0;
        out[(size_t)row * TT + t] = (float)sp;
        hist = (hist << 1) | (unsigned)sp;
    }
}

extern "C" void kernel_launch(void* const* d_in, const int* in_sizes, int n_in,
                              void* d_out, int out_size, void* d_ws, size_t ws_size,
                              hipStream_t stream) {
    const float* x  = (const float*)d_in[0];
    const float* w1 = (const float*)d_in[1];
    const float* w2 = (const float*)d_in[2];
    float* out = (float*)d_out;
    char* ws = (char*)d_ws;

    double* cst  = (double*)(ws + OFF_CONST);
    double* z1   = (double*)(ws + OFF_Z1);
    double* u1   = (double*)(ws + OFF_U1);
    double* z2   = (double*)(ws + OFF_Z2);
    double* u2   = (double*)(ws + OFF_U2);
    float*  s1   = (float*) (ws + OFF_S1);
    u64*    fbm  = (u64*)   (ws + OFF_FBM);
    float*  part = (float*) (ws + OFF_PART);

    k0_init<<<1, 128, 0, stream>>>(cst);

    if (ws_size >= NEED_SPARSE) {
        int blocks = (BB * F1 * 64 + 255) / 256;     /* 31200: one wave per (b,f) */
        k1_fbm<<<blocks, 256, 0, stream>>>(x, fbm);
        k3o<<<dim3(NF, NOC, BB), 320, 0, stream>>>(w1, fbm, part);
        k4_sum<<<dim3(TT, BB), 256, 0, stream>>>(part, z1);
    } else {
        k_dense_gemm1<<<250, 256, 0, stream>>>(x, w1, z1);
    }

    k5_psp<<<BB * O1, 320, 0, stream>>>(z1, u1, cst);
    k6_spike1<<<(BB * O1 + 63) / 64, 64, 0, stream>>>(u1, s1, cst);
    k7_gemm2<<<BB * O2N, 320, 0, stream>>>(s1, w2, z2);
    k5_psp<<<BB * O2N, 320, 0, stream>>>(z2, u2, cst);
    k9_spike2<<<(BB * O2N + 63) / 64, 64, 0, stream>>>(u2, out, cst);
    (void)in_sizes; (void)n_in; (void)out_size;
}

// Round 4
// 513.466 us; speedup vs baseline: 4.5753x; 4.5753x over previous
//
#include <hip/hip_runtime.h>

#define F1 62400
#define O1 800
#define O2N 100
#define TT 300
#define BB 2
#define NWRD 975        /* 64-bit f-words */
#define KSRM 77
#define KREF 11
#define MB 25           /* M-blocks of 32 o */
#define KS 25           /* K-splits of 39 words */
#define WPS 39          /* words per K-split */
#define NPAD 640        /* n = b*320 + t, t padded 300->320 */

typedef unsigned long long u64;
typedef int i32x4 __attribute__((ext_vector_type(4)));

/* ---- ws layout (bytes) ---- */
#define OFF_CONST 0ull
#define OFF_Z1   1024ull
#define OFF_U1   (OFF_Z1 + 3840000ull)
#define OFF_Z2   (OFF_U1 + 3840000ull)
#define OFF_U2   (OFF_Z2 + 480000ull)
#define OFF_S1   (OFF_U2 + 480000ull)
#define OFF_XBW  (OFF_S1 + 1920000ull)
#define OFF_PART (OFF_XBW + 4680000ull)          /* xbw: 975*600*8 */
#define NEED_SPARSE (OFF_PART + 102400000ull)    /* part: 25*25*32*640*8 ~ 112 MB (ws>=219MB proven R2) */

/* K0: SRM/REF kernels, fp64 rounded through fp32 (matches np.float32). */
__global__ void k0_init(double* c) {
    int k = threadIdx.x;
    if (k < KSRM) {
        double v = ((double)k / 10.0) * exp(1.0 - (double)k / 10.0);
        c[k] = (double)(float)v;
    }
    if (k < KREF) {
        double v = -20.0 * (double)k * exp(1.0 - (double)k);
        c[80 + k] = (double)(float)v;
    }
}

/* K1: bitmask xbw[w][b][t]: bit j = (x[b][w*64+j][t] > 0.5). Wave=(b,fw,tg),
   lane=t: coalesced loads AND coalesced u64 stores. */
__global__ __launch_bounds__(256) void k1_xbw(const float* __restrict__ x,
                                              u64* __restrict__ xbw) {
    const int NTG = 5;
    int gw = (blockIdx.x * 256 + threadIdx.x) >> 6;
    int lane = threadIdx.x & 63;
    if (gw >= BB * NWRD * NTG) return;
    int b  = gw / (NWRD * NTG);
    int r  = gw % (NWRD * NTG);
    int fw = r / NTG;
    int tg = r % NTG;
    int t = tg * 64 + lane;
    bool act = (t < TT);
    int tc = act ? t : 0;
    const float* xp = x + ((size_t)(b * F1 + (fw << 6))) * TT + tc;
    unsigned lo = 0, hi = 0;
    #pragma unroll
    for (int j = 0; j < 32; ++j)
        lo |= (xp[(size_t)j * TT] > 0.5f ? 1u : 0u) << j;
    #pragma unroll
    for (int j = 0; j < 32; ++j)
        hi |= (xp[(size_t)(j + 32) * TT] > 0.5f ? 1u : 0u) << j;
    if (act)
        xbw[(size_t)fw * (BB * TT) + b * TT + t] = ((u64)hi << 32) | lo;
}

/* K3m: exact fixed-point i8 MFMA GEMM.
   z1_int[o][n] = sum_d 2^(8d) * (x . digit_d(rint(w1*2^31))), all exact.
   Block: 32 o x 640 n, K-chunk = 39 words of 64 f. 8 waves: wave
   (oh=wid>>2, q=wid&3) owns o-half oh, n-quarter q (10 16x16 tiles x 4 digits).
   A/B frag layout: row/col = l&15, k = (l>>4)*16 + j.
   C/D (m89-verified): col = l&15, row = (l>>4)*4 + reg. */
__global__ __launch_bounds__(512, 2) void k3m(const float* __restrict__ w1,
                                              const u64* __restrict__ xbw,
                                              double* __restrict__ part) {
    __shared__ __align__(16) unsigned char As[4 * 4 * 32 * 16];  /* [dig][kb][o][16] 8KB */
    __shared__ __align__(16) unsigned char Bs[NPAD * 80];        /* [n][80], 64 used    */
    int m = blockIdx.x, ks = blockIdx.y;
    int tid = threadIdx.x;
    int l = tid & 63, wid = tid >> 6;
    int q = wid & 3, oh = wid >> 2;

    i32x4 acc[10][4];
    #pragma unroll
    for (int i = 0; i < 10; ++i)
        #pragma unroll
        for (int d = 0; d < 4; ++d)
            acc[i][d] = (i32x4){0, 0, 0, 0};

    int ao = tid >> 4;              /* 0..31: o row this thread stages   */
    int kq = tid & 15;              /* covers k = kq*4 .. kq*4+3          */
    const int kb = kq >> 2, klo4 = (kq & 3) * 4;

    for (int s = 0; s < WPS; ++s) {
        int w = ks * WPS + s;
        __syncthreads();
        /* ---- stage A: load 4 w1 floats, quantize (double, exact), split digits ---- */
        {
            const float* src = w1 + (size_t)(m * 32 + ao) * F1 + (size_t)w * 64 + kq * 4;
            float4 v4 = *(const float4*)src;
            float vv[4] = {v4.x, v4.y, v4.z, v4.w};
            unsigned dw[4] = {0, 0, 0, 0};
            #pragma unroll
            for (int j = 0; j < 4; ++j) {
                int v = (int)rint((double)vv[j] * 2147483648.0);
                int d0 = (int)(signed char)(v & 0xFF); v = (v - d0) >> 8;
                int d1 = (int)(signed char)(v & 0xFF); v = (v - d1) >> 8;
                int d2 = (int)(signed char)(v & 0xFF); v = (v - d2) >> 8;
                int d3 = v;
                dw[0] |= (unsigned)(d0 & 0xFF) << (8 * j);
                dw[1] |= (unsigned)(d1 & 0xFF) << (8 * j);
                dw[2] |= (unsigned)(d2 & 0xFF) << (8 * j);
                dw[3] |= (unsigned)(d3 & 0xFF) << (8 * j);
            }
            #pragma unroll
            for (int dig = 0; dig < 4; ++dig)
                *(unsigned*)&As[dig * 2048 + kb * 512 + ao * 16 + klo4] = dw[dig];
        }
        /* ---- stage B: unpack 64 t-bits -> 64 i8 per n ---- */
        for (int n = tid; n < NPAD; n += 512) {
            int b = (n >= 320) ? 1 : 0;
            int t = n - b * 320;
            if (t < TT) {
                u64 bits = xbw[(size_t)w * (BB * TT) + b * TT + t];
                unsigned d[16];
                #pragma unroll
                for (int i = 0; i < 16; ++i)
                    d[i] = ((unsigned)((bits >> (4 * i)) & 0xFull) * 0x00204081u) & 0x01010101u;
                #pragma unroll
                for (int j = 0; j < 4; ++j) {
                    i32x4 v = {(int)d[4 * j], (int)d[4 * j + 1],
                               (int)d[4 * j + 2], (int)d[4 * j + 3]};
                    *(i32x4*)&Bs[n * 80 + j * 16] = v;
                }
            } else {
                i32x4 zz = {0, 0, 0, 0};
                #pragma unroll
                for (int j = 0; j < 4; ++j) *(i32x4*)&Bs[n * 80 + j * 16] = zz;
            }
        }
        __syncthreads();
        /* ---- compute: 4 A-frags, 10 n-tiles x 4 digit-MFMA ---- */
        i32x4 a[4];
        #pragma unroll
        for (int dig = 0; dig < 4; ++dig)
            a[dig] = *(i32x4*)&As[dig * 2048 + (l >> 4) * 512 + (oh * 16 + (l & 15)) * 16];
        #pragma unroll
        for (int tt = 0; tt < 10; ++tt) {
            int n = q * 160 + tt * 16 + (l & 15);
            i32x4 bf = *(i32x4*)&Bs[n * 80 + (l >> 4) * 16];
            #pragma unroll
            for (int dig = 0; dig < 4; ++dig)
                acc[tt][dig] = __builtin_amdgcn_mfma_i32_16x16x64_i8(a[dig], bf,
                                                                    acc[tt][dig], 0, 0, 0);
        }
    }

    /* ---- epilogue: combine digits exactly in i64 -> double partial ---- */
    size_t pbase = (size_t)(m * KS + ks) * 32 * NPAD;
    #pragma unroll
    for (int tt = 0; tt < 10; ++tt) {
        int n = q * 160 + tt * 16 + (l & 15);
        #pragma unroll
        for (int r = 0; r < 4; ++r) {
            int o = oh * 16 + (l >> 4) * 4 + r;
            long long c = (long long)acc[tt][0][r]
                        + ((long long)acc[tt][1][r] << 8)
                        + ((long long)acc[tt][2][r] << 16)
                        + ((long long)acc[tt][3][r] << 24);
            part[pbase + (size_t)o * NPAD + n] = (double)c;
        }
    }
}

/* K4s: z1[(b*800+o)][t] = 2^-31 * sum_ks part (fp64, exact) */
__global__ __launch_bounds__(320) void k4s(const double* __restrict__ part,
                                           double* __restrict__ z1) {
    int og = blockIdx.x;             /* 0..799 */
    int t = threadIdx.x; if (t >= TT) return;
    int m = og >> 5, ol = og & 31;
    #pragma unroll
    for (int b = 0; b < BB; ++b) {
        double s = 0.0;
        for (int ks = 0; ks < KS; ++ks)
            s += part[((size_t)(m * KS + ks) * 32 + ol) * NPAD + b * 320 + t];
        z1[((size_t)(b * O1 + og)) * TT + t] = s * 4.656612873077393e-10;
    }
}

/* dense fallback GEMM1 (used only if ws too small) */
__global__ __launch_bounds__(256) void k_dense_gemm1(const float* __restrict__ x,
                                                     const float* __restrict__ w1,
                                                     double* __restrict__ z1) {
    int lin = blockIdx.x;
    int ot = lin % 25; int tt = (lin / 25) % 5; int b = lin / 125;
    int t0 = tt * 64, o0 = ot * 32;
    __shared__ float xs[64][64];
    __shared__ float wsh[32][64];
    int ti = threadIdx.x & 63, og = threadIdx.x >> 6;
    double dacc[8] = {0, 0, 0, 0, 0, 0, 0, 0};
    for (int fc = 0; fc < F1; fc += 64) {
        __syncthreads();
        for (int e = threadIdx.x; e < 64 * 64; e += 256) {
            int r = e >> 6, c = e & 63;
            int t = t0 + c;
            xs[r][c] = (t < TT) ? x[((size_t)b * F1 + fc + r) * TT + t] : 0.0f;
        }
        for (int e = threadIdx.x; e < 32 * 64; e += 256) {
            int r = e >> 6, c = e & 63;
            wsh[r][c] = w1[(size_t)(o0 + r) * F1 + fc + c];
        }
        __syncthreads();
        float facc[8] = {0, 0, 0, 0, 0, 0, 0, 0};
        for (int ff = 0; ff < 64; ++ff) {
            float xv = xs[ff][ti];
            #pragma unroll
            for (int oo = 0; oo < 8; ++oo) facc[oo] += wsh[og * 8 + oo][ff] * xv;
        }
        #pragma unroll
        for (int oo = 0; oo < 8; ++oo) dacc[oo] += (double)facc[oo];
    }
    int t = t0 + ti;
    if (t < TT) {
        #pragma unroll
        for (int oo = 0; oo < 8; ++oo) {
            int o = o0 + og * 8 + oo;
            z1[((size_t)(b * O1 + o)) * TT + t] = dacc[oo];
        }
    }
}

/* K5: causal SRM-alpha conv (psp), fp64 */
__global__ __launch_bounds__(320) void k5_psp(const double* __restrict__ z,
                                              double* __restrict__ u,
                                              const double* __restrict__ cst) {
    int row = blockIdx.x;
    int t = threadIdx.x; if (t >= TT) return;
    const double* zr = z + (size_t)row * TT;
    int kmax = t < (KSRM - 1) ? t : (KSRM - 1);
    double acc = 0.0;
    for (int k = 0; k <= kmax; ++k) acc += cst[k] * zr[t - k];
    u[(size_t)row * TT + t] = acc;
}

/* K6: spike scan layer 1 -> s1 (b,t,f) */
__global__ __launch_bounds__(64) void k6_spike1(const double* __restrict__ u,
                                                float* __restrict__ s_out,
                                                const double* __restrict__ cst) {
    int row = blockIdx.x * 64 + threadIdx.x;
    if (row >= BB * O1) return;
    int b = row / O1, o = row % O1;
    double rk[KREF];
    #pragma unroll
    for (int d = 0; d < KREF; ++d) rk[d] = cst[80 + d];
    const double* ur = u + (size_t)row * TT;
    unsigned hist = 0;
    for (int t = 0; t < TT; ++t) {
        double ueff = ur[t];
        #pragma unroll
        for (int d = 1; d < KREF; ++d)
            if (hist & (1u << (d - 1))) ueff += rk[d];
        int sp = (ueff >= 10.0) ? 1 : 0;
        s_out[((size_t)(b * TT + t)) * O1 + o] = (float)sp;
        hist = (hist << 1) | (unsigned)sp;
    }
}

/* K7: GEMM2, fp64 acc */
__global__ __launch_bounds__(320) void k7_gemm2(const float* __restrict__ s1,
                                                const float* __restrict__ w2,
                                                double* __restrict__ z2) {
    int bo = blockIdx.x;
    int t = threadIdx.x; if (t >= TT) return;
    int b = bo / O2N, o2 = bo % O2N;
    const float* srow = s1 + ((size_t)(b * TT + t)) * O1;
    const float* wrow = w2 + (size_t)o2 * O1;
    double acc = 0.0;
    for (int f = 0; f < O1; ++f) acc += (double)(wrow[f] * srow[f]);
    z2[(size_t)bo * TT + t] = acc;
}

/* K9: spike scan layer 2 -> output (b,o2,t) fp32 */
__global__ __launch_bounds__(64) void k9_spike2(const double* __restrict__ u,
                                                float* __restrict__ out,
                                                const double* __restrict__ cst) {
    int row = blockIdx.x * 64 + threadIdx.x;
    if (row >= BB * O2N) return;
    double rk[KREF];
    #pragma unroll
    for (int d = 0; d < KREF; ++d) rk[d] = cst[80 + d];
    const double* ur = u + (size_t)row * TT;
    unsigned hist = 0;
    for (int t = 0; t < TT; ++t) {
        double ueff = ur[t];
        #pragma unroll
        for (int d = 1; d < KREF; ++d)
            if (hist & (1u << (d - 1))) ueff += rk[d];
        int sp = (ueff >= 10.0) ? 1 : 0;
        out[(size_t)row * TT + t] = (float)sp;
        hist = (hist << 1) | (unsigned)sp;
    }
}

extern "C" void kernel_launch(void* const* d_in, const int* in_sizes, int n_in,
                              void* d_out, int out_size, void* d_ws, size_t ws_size,
                              hipStream_t stream) {
    const float* x  = (const float*)d_in[0];
    const float* w1 = (const float*)d_in[1];
    const float* w2 = (const float*)d_in[2];
    float* out = (float*)d_out;
    char* ws = (char*)d_ws;

    double* cst  = (double*)(ws + OFF_CONST);
    double* z1   = (double*)(ws + OFF_Z1);
    double* u1   = (double*)(ws + OFF_U1);
    double* z2   = (double*)(ws + OFF_Z2);
    double* u2   = (double*)(ws + OFF_U2);
    float*  s1   = (float*) (ws + OFF_S1);
    u64*    xbw  = (u64*)   (ws + OFF_XBW);
    double* part = (double*)(ws + OFF_PART);

    k0_init<<<1, 128, 0, stream>>>(cst);

    if (ws_size >= NEED_SPARSE) {
        int blocks = (BB * NWRD * 5 * 64 + 255) / 256;   /* 2438 */
        k1_xbw<<<blocks, 256, 0, stream>>>(x, xbw);
        k3m<<<dim3(MB, KS), 512, 0, stream>>>(w1, xbw, part);
        k4s<<<O1, 320, 0, stream>>>(part, z1);
    } else {
        k_dense_gemm1<<<250, 256, 0, stream>>>(x, w1, z1);
    }

    k5_psp<<<BB * O1, 320, 0, stream>>>(z1, u1, cst);
    k6_spike1<<<(BB * O1 + 63) / 64, 64, 0, stream>>>(u1, s1, cst);
    k7_gemm2<<<BB * O2N, 320, 0, stream>>>(s1, w2, z2);
    k5_psp<<<BB * O2N, 320, 0, stream>>>(z2, u2, cst);
    k9_spike2<<<(BB * O2N + 63) / 64, 64, 0, stream>>>(u2, out, cst);
    (void)in_sizes; (void)n_in; (void)out_size;
}